// Round 2
// baseline (404.522 us; speedup 1.0000x reference)
//
#include <hip/hip_runtime.h>

#define N_NODES 250
#define IN_F    18
#define OUT_F   48
#define E_EDGES 4000
#define E_TOT   (E_EDGES + N_NODES)

// Workspace layout (float offsets):
//   h      [0, 12000)       GAT hidden  h = x @ Wg^T          [250*48]
//   a_s    [12000, 12250)   per-node src attention logits
//   a_d    [12250, 12500)   per-node dst attention logits
//   denom  [12500, 12750)   softmax denominators
//   ex     [12750, 17000)   per-edge exp values
//   vraw   [17000, 29000)   GAT out accumulator (init = b_gat), pre-relu
//   v1     [29000, 33028)   [roh(8), pssm(20), relu(W0@v+b0)(4000)]
//   v2     [33028, 33828)   relu(W1@v1+b1)
//   v2b    [33828, 34228)   relu(W2@v2+b2)
//   v3     [34228, 34428)   relu(W3@v2b+b3)
#define WS_H     0
#define WS_AS    12000
#define WS_AD    12250
#define WS_DEN   12500
#define WS_EX    12750
#define WS_VRAW  17000
#define WS_V1    29000
#define WS_V2    33028
#define WS_V2B   33828
#define WS_V3    34228

// ---------------------------------------------------------------------------
// K1: per-node prep. grid=250 blocks, 64 threads.
//  h[n][f] = dot(x[n,:], Wg[f,:]);  a_s[n] = dot(h[n], att_src); a_d likewise.
//  Also: denom[n]=0, vraw[n][f]=b_gat[f], block0 writes the 28 concat consts.
__global__ void k1_prep(const float* __restrict__ x, const float* __restrict__ wg,
                        const float* __restrict__ att_src, const float* __restrict__ att_dst,
                        const float* __restrict__ b_gat,
                        const float* __restrict__ roh, const float* __restrict__ pssm,
                        float* __restrict__ ws) {
    const int n = blockIdx.x;
    const int f = threadIdx.x;
    float hv = 0.f;
    if (f < OUT_F) {
        const float* xr = x + n * IN_F;
        const float* wr = wg + f * IN_F;
        #pragma unroll
        for (int k = 0; k < IN_F; ++k) hv += xr[k] * wr[k];
        ws[WS_H + n * OUT_F + f]    = hv;
        ws[WS_VRAW + n * OUT_F + f] = b_gat[f];
    }
    float cs = (f < OUT_F) ? hv * att_src[f] : 0.f;
    float cd = (f < OUT_F) ? hv * att_dst[f] : 0.f;
    #pragma unroll
    for (int o = 32; o > 0; o >>= 1) {
        cs += __shfl_down(cs, o);
        cd += __shfl_down(cd, o);
    }
    if (f == 0) {
        ws[WS_AS + n] = cs;
        ws[WS_AD + n] = cd;
        ws[WS_DEN + n] = 0.f;
    }
    if (n == 0 && f < 28) ws[WS_V1 + f] = (f < 8) ? roh[f] : pssm[f - 8];
}

// ---------------------------------------------------------------------------
// K2: per-edge exp + denominator. (max-subtraction dropped: softmax is
// shift-invariant and logits are bounded ~|6| here, exp safe in fp32)
__global__ void k2_edge(const int* __restrict__ ei, float* __restrict__ ws) {
    const int e = blockIdx.x * blockDim.x + threadIdx.x;
    if (e >= E_TOT) return;
    int s, d;
    if (e < E_EDGES) { s = ei[e]; d = ei[E_EDGES + e]; }
    else             { s = d = e - E_EDGES; }
    float val = ws[WS_AS + s] + ws[WS_AD + d];
    val = (val > 0.f) ? val : 0.2f * val;          // leaky_relu 0.2
    float ex = expf(val);
    atomicAdd(ws + WS_DEN + d, ex);
    ws[WS_EX + e] = ex;
}

// ---------------------------------------------------------------------------
// K3: per-(edge, feature) weighted scatter into vraw. t = e*48 + f packing
// (no idle lanes except final partial block).
__global__ void k3_accum(const int* __restrict__ ei, float* __restrict__ ws) {
    const int t = blockIdx.x * blockDim.x + threadIdx.x;
    const int e = t / OUT_F;
    const int f = t - e * OUT_F;
    if (e >= E_TOT) return;
    int s, d;
    if (e < E_EDGES) { s = ei[e]; d = ei[E_EDGES + e]; }
    else             { s = d = e - E_EDGES; }
    const float alpha = ws[WS_EX + e] / (ws[WS_DEN + d] + 1e-16f);
    atomicAdd(ws + WS_VRAW + d * OUT_F + f, alpha * ws[WS_H + s * OUT_F + f]);
}

// ---------------------------------------------------------------------------
// Generic row-parallel matvec: one 64-lane wave per output row.
// C must be a multiple of 4. RELU_IN applies relu to the input vector on load
// (used to fold GAT's final bias+relu into the W0 read — idempotent).
template <int C, bool RELU_IN, bool RELU_OUT>
__global__ void matvec(const float* __restrict__ W, const float* __restrict__ b,
                       const float* __restrict__ vin, float* __restrict__ vout,
                       int rows) {
    const int wv   = threadIdx.x >> 6;
    const int lane = threadIdx.x & 63;
    const int row  = blockIdx.x * (blockDim.x >> 6) + wv;
    if (row >= rows) return;
    const float4* Wr = reinterpret_cast<const float4*>(W + (size_t)row * C);
    const float4* vi = reinterpret_cast<const float4*>(vin);
    constexpr int C4 = C / 4;
    float acc = 0.f;
    for (int i = lane; i < C4; i += 64) {
        float4 w = Wr[i];
        float4 v = vi[i];
        if (RELU_IN) {
            v.x = fmaxf(v.x, 0.f); v.y = fmaxf(v.y, 0.f);
            v.z = fmaxf(v.z, 0.f); v.w = fmaxf(v.w, 0.f);
        }
        acc += w.x * v.x + w.y * v.y + w.z * v.z + w.w * v.w;
    }
    #pragma unroll
    for (int o = 32; o > 0; o >>= 1) acc += __shfl_down(acc, o);
    if (lane == 0) {
        float r = acc + b[row];
        vout[row] = RELU_OUT ? fmaxf(r, 0.f) : r;
    }
}

// ---------------------------------------------------------------------------
// Tail: W3 (200x400) + W4 (1x200) fused in a single block (4 waves).
__global__ void k_tail(const float* __restrict__ W3, const float* __restrict__ b3,
                       const float* __restrict__ W4, const float* __restrict__ b4,
                       float* __restrict__ ws, float* __restrict__ out) {
    const int wv   = threadIdx.x >> 6;
    const int lane = threadIdx.x & 63;
    const float* v2b = ws + WS_V2B;   // W2 output, 400
    float*       v3  = ws + WS_V3;    // W3 output, 200
    for (int row = wv; row < 200; row += 4) {
        const float4* Wr = reinterpret_cast<const float4*>(W3 + row * 400);
        const float4* vi = reinterpret_cast<const float4*>(v2b);
        float acc = 0.f;
        for (int i = lane; i < 100; i += 64) {
            float4 w = Wr[i], v = vi[i];
            acc += w.x * v.x + w.y * v.y + w.z * v.z + w.w * v.w;
        }
        #pragma unroll
        for (int o = 32; o > 0; o >>= 1) acc += __shfl_down(acc, o);
        if (lane == 0) v3[row] = fmaxf(acc + b3[row], 0.f);
    }
    __syncthreads();
    if (wv == 0) {
        const float4* W4v = reinterpret_cast<const float4*>(W4);
        const float4* v3v = reinterpret_cast<const float4*>(v3);
        float acc = 0.f;
        for (int i = lane; i < 50; i += 64) {
            float4 w = W4v[i], v = v3v[i];
            acc += w.x * v.x + w.y * v.y + w.z * v.z + w.w * v.w;
        }
        #pragma unroll
        for (int o = 32; o > 0; o >>= 1) acc += __shfl_down(acc, o);
        if (lane == 0) out[0] = acc + b4[0];
    }
}

// ---------------------------------------------------------------------------
extern "C" void kernel_launch(void* const* d_in, const int* in_sizes, int n_in,
                              void* d_out, int out_size, void* d_ws, size_t ws_size,
                              hipStream_t stream) {
    const float* x       = (const float*)d_in[0];
    const int*   ei      = (const int*)  d_in[1];
    // d_in[2] = edge_weight (unused by reference)
    const float* roh     = (const float*)d_in[3];
    const float* pssm    = (const float*)d_in[4];
    const float* wg      = (const float*)d_in[5];
    const float* att_src = (const float*)d_in[6];
    const float* att_dst = (const float*)d_in[7];
    const float* b_gat   = (const float*)d_in[8];
    const float* W0 = (const float*)d_in[9];   const float* b0 = (const float*)d_in[10];
    const float* W1 = (const float*)d_in[11];  const float* b1 = (const float*)d_in[12];
    const float* W2 = (const float*)d_in[13];  const float* b2 = (const float*)d_in[14];
    const float* W3 = (const float*)d_in[15];  const float* b3 = (const float*)d_in[16];
    const float* W4 = (const float*)d_in[17];  const float* b4 = (const float*)d_in[18];

    float* ws  = (float*)d_ws;
    float* out = (float*)d_out;

    // GAT
    k1_prep<<<N_NODES, 64, 0, stream>>>(x, wg, att_src, att_dst, b_gat, roh, pssm, ws);
    k2_edge<<<(E_TOT + 255) / 256, 256, 0, stream>>>(ei, ws);
    k3_accum<<<(E_TOT * OUT_F + 255) / 256, 256, 0, stream>>>(ei, ws);

    // MLP
    // W0: 4000x12000, input = relu(vraw) folded into load, relu out -> v1[28:]
    matvec<12000, true,  true><<<1000, 256, 0, stream>>>(W0, b0, ws + WS_VRAW, ws + WS_V1 + 28, 4000);
    // W1: 800x4028
    matvec<4028,  false, true><<<200,  256, 0, stream>>>(W1, b1, ws + WS_V1, ws + WS_V2, 800);
    // W2: 400x800
    matvec<800,   false, true><<<100,  256, 0, stream>>>(W2, b2, ws + WS_V2, ws + WS_V2B, 400);
    // W3 + W4 fused
    k_tail<<<1, 256, 0, stream>>>(W3, b3, W4, b4, ws, out);
}

// Round 4
// 329.953 us; speedup vs baseline: 1.2260x; 1.2260x over previous
//
#include <hip/hip_runtime.h>

#define N_NODES 250
#define IN_F    18
#define OUT_F   48
#define E_EDGES 4000
#define E_TOT   (E_EDGES + N_NODES)

// Workspace layout (float offsets):
//   h      [0, 12000)       GAT hidden  h = x @ Wg^T          [250*48]
//   a_s    [12000, 12250)   per-node src attention logits
//   a_d    [12250, 12500)   per-node dst attention logits
//   denom  [12500, 12750)   softmax denominators
//   ex     [12750, 17000)   per-edge exp values
//   vraw   [17000, 29000)   GAT out accumulator (init = b_gat), pre-relu
//   v1     [29000, 33028)   [roh(8), pssm(20), relu(W0@v+b0)(4000)]
//   v2     [33028, 33828)   relu(W1@v1+b1)
//   v2b    [33828, 34228)   relu(W2@v2+b2)
//   v3     [34228, 34428)   relu(W3@v2b+b3)
#define WS_H     0
#define WS_AS    12000
#define WS_AD    12250
#define WS_DEN   12500
#define WS_EX    12750
#define WS_VRAW  17000
#define WS_V1    29000
#define WS_V2    33028
#define WS_V2B   33828
#define WS_V3    34228

// ---------------------------------------------------------------------------
// K1: per-node prep. grid=250 blocks, 64 threads.
__global__ void k1_prep(const float* __restrict__ x, const float* __restrict__ wg,
                        const float* __restrict__ att_src, const float* __restrict__ att_dst,
                        const float* __restrict__ b_gat,
                        const float* __restrict__ roh, const float* __restrict__ pssm,
                        float* __restrict__ ws) {
    const int n = blockIdx.x;
    const int f = threadIdx.x;
    float hv = 0.f;
    if (f < OUT_F) {
        const float* xr = x + n * IN_F;
        const float* wr = wg + f * IN_F;
        #pragma unroll
        for (int k = 0; k < IN_F; ++k) hv += xr[k] * wr[k];
        ws[WS_H + n * OUT_F + f]    = hv;
        ws[WS_VRAW + n * OUT_F + f] = b_gat[f];
    }
    float cs = (f < OUT_F) ? hv * att_src[f] : 0.f;
    float cd = (f < OUT_F) ? hv * att_dst[f] : 0.f;
    #pragma unroll
    for (int o = 32; o > 0; o >>= 1) {
        cs += __shfl_down(cs, o);
        cd += __shfl_down(cd, o);
    }
    if (f == 0) {
        ws[WS_AS + n] = cs;
        ws[WS_AD + n] = cd;
        ws[WS_DEN + n] = 0.f;
    }
    if (n == 0 && f < 28) ws[WS_V1 + f] = (f < 8) ? roh[f] : pssm[f - 8];
}

// ---------------------------------------------------------------------------
// K2: per-edge exp + denominator. (segment_max dropped: softmax is
// shift-invariant; logits bounded ~|6|, exp safe in fp32)
__global__ void k2_edge(const int* __restrict__ ei, float* __restrict__ ws) {
    const int e = blockIdx.x * blockDim.x + threadIdx.x;
    if (e >= E_TOT) return;
    int s, d;
    if (e < E_EDGES) { s = ei[e]; d = ei[E_EDGES + e]; }
    else             { s = d = e - E_EDGES; }
    float val = ws[WS_AS + s] + ws[WS_AD + d];
    val = (val > 0.f) ? val : 0.2f * val;          // leaky_relu 0.2
    float ex = expf(val);
    atomicAdd(ws + WS_DEN + d, ex);
    ws[WS_EX + e] = ex;
}

// ---------------------------------------------------------------------------
// K3: per-(edge, feature) weighted scatter into vraw.
__global__ void k3_accum(const int* __restrict__ ei, float* __restrict__ ws) {
    const int t = blockIdx.x * blockDim.x + threadIdx.x;
    const int e = t / OUT_F;
    const int f = t - e * OUT_F;
    if (e >= E_TOT) return;
    int s, d;
    if (e < E_EDGES) { s = ei[e]; d = ei[E_EDGES + e]; }
    else             { s = d = e - E_EDGES; }
    const float alpha = ws[WS_EX + e] / (ws[WS_DEN + d] + 1e-16f);
    atomicAdd(ws + WS_VRAW + d * OUT_F + f, alpha * ws[WS_H + s * OUT_F + f]);
}

// ---------------------------------------------------------------------------
// Row-parallel matvec: one 64-lane wave per output row, float4 loads,
// single accumulator (add order fixed -> deterministic), unroll for load ILP.
template <int C, bool RELU_IN, bool RELU_OUT>
__global__ void matvec(const float* __restrict__ W, const float* __restrict__ b,
                       const float* __restrict__ vin, float* __restrict__ vout,
                       int rows) {
    const int wv   = threadIdx.x >> 6;
    const int lane = threadIdx.x & 63;
    const int row  = blockIdx.x * (blockDim.x >> 6) + wv;
    if (row >= rows) return;
    const float4* Wr = reinterpret_cast<const float4*>(W + (size_t)row * C);
    const float4* vi = reinterpret_cast<const float4*>(vin);
    constexpr int C4 = C / 4;
    float acc = 0.f;
    #pragma unroll 4
    for (int i = lane; i < C4; i += 64) {
        float4 w = Wr[i];
        float4 v = vi[i];
        if (RELU_IN) {
            v.x = fmaxf(v.x, 0.f); v.y = fmaxf(v.y, 0.f);
            v.z = fmaxf(v.z, 0.f); v.w = fmaxf(v.w, 0.f);
        }
        acc += w.x * v.x + w.y * v.y + w.z * v.z + w.w * v.w;
    }
    #pragma unroll
    for (int o = 32; o > 0; o >>= 1) acc += __shfl_down(acc, o);
    if (lane == 0) {
        float r = acc + b[row];
        vout[row] = RELU_OUT ? fmaxf(r, 0.f) : r;
    }
}

// ---------------------------------------------------------------------------
// Final layer: W4 (1x200) dot — one wave.
__global__ void k_w4(const float* __restrict__ W4, const float* __restrict__ b4,
                     const float* __restrict__ v3, float* __restrict__ out) {
    const int lane = threadIdx.x & 63;
    const float4* W4v = reinterpret_cast<const float4*>(W4);
    const float4* v3v = reinterpret_cast<const float4*>(v3);
    float acc = 0.f;
    for (int i = lane; i < 50; i += 64) {
        float4 w = W4v[i], v = v3v[i];
        acc += w.x * v.x + w.y * v.y + w.z * v.z + w.w * v.w;
    }
    #pragma unroll
    for (int o = 32; o > 0; o >>= 1) acc += __shfl_down(acc, o);
    if (lane == 0) out[0] = acc + b4[0];
}

// ---------------------------------------------------------------------------
extern "C" void kernel_launch(void* const* d_in, const int* in_sizes, int n_in,
                              void* d_out, int out_size, void* d_ws, size_t ws_size,
                              hipStream_t stream) {
    const float* x       = (const float*)d_in[0];
    const int*   ei      = (const int*)  d_in[1];
    // d_in[2] = edge_weight (unused by reference)
    const float* roh     = (const float*)d_in[3];
    const float* pssm    = (const float*)d_in[4];
    const float* wg      = (const float*)d_in[5];
    const float* att_src = (const float*)d_in[6];
    const float* att_dst = (const float*)d_in[7];
    const float* b_gat   = (const float*)d_in[8];
    const float* W0 = (const float*)d_in[9];   const float* b0 = (const float*)d_in[10];
    const float* W1 = (const float*)d_in[11];  const float* b1 = (const float*)d_in[12];
    const float* W2 = (const float*)d_in[13];  const float* b2 = (const float*)d_in[14];
    const float* W3 = (const float*)d_in[15];  const float* b3 = (const float*)d_in[16];
    const float* W4 = (const float*)d_in[17];  const float* b4 = (const float*)d_in[18];

    float* ws  = (float*)d_ws;
    float* out = (float*)d_out;

    // GAT
    k1_prep<<<N_NODES, 64, 0, stream>>>(x, wg, att_src, att_dst, b_gat, roh, pssm, ws);
    k2_edge<<<(E_TOT + 255) / 256, 256, 0, stream>>>(ei, ws);
    k3_accum<<<(E_TOT * OUT_F + 255) / 256, 256, 0, stream>>>(ei, ws);

    // MLP
    // W0: 4000x12000, relu(GAT out) folded into load, relu out -> v1[28:]
    matvec<12000, true,  true><<<1000, 256, 0, stream>>>(W0, b0, ws + WS_VRAW, ws + WS_V1 + 28, 4000);
    // W1: 800x4028
    matvec<4028,  false, true><<<200,  256, 0, stream>>>(W1, b1, ws + WS_V1, ws + WS_V2, 800);
    // W2: 400x800
    matvec<800,   false, true><<<100,  256, 0, stream>>>(W2, b2, ws + WS_V2, ws + WS_V2B, 400);
    // W3: 200x400 (was single-block k_tail -> now 50 blocks, ~200 waves)
    matvec<400,   false, true><<<50,   256, 0, stream>>>(W3, b3, ws + WS_V2B, ws + WS_V3, 200);
    // W4: 1x200 final dot
    k_w4<<<1, 64, 0, stream>>>(W4, b4, ws + WS_V3, out);
}

// Round 10
// 318.435 us; speedup vs baseline: 1.2703x; 1.0362x over previous
//
#include <hip/hip_runtime.h>

#define N_NODES 250
#define IN_F    18
#define OUT_F   48
#define E_EDGES 4000
#define E_TOT   (E_EDGES + N_NODES)
#define EPS_F   1e-16f

typedef float fx4 __attribute__((ext_vector_type(4)));  // clang vector: valid for __builtin_nontemporal_load

// Workspace layout (float offsets):
//   h      [0, 12000)        GAT hidden  h = x @ Wg^T      [250*48]
//   a_s    [12000, 12250)    per-node src attention logits
//   a_d    [12250, 12500)    per-node dst attention logits
//   ex     [12500, 16750)    per-edge exp values
//   rowp   [16750, 17001)    CSR row_ptr (ints)
//   slots  [17004, 21254)    CSR slot -> edge id (ints)
//   vraw   [21504, 33504)    GAT out (bias added, pre-relu)
//   v1     [33504, 37532)    [roh(8), pssm(20), relu(W0@v+b0)(4000)]
//   v2     [37532, 38332)    relu(W1@v1+b1)
//   v2b    [38332, 38732)    relu(W2@v2+b2)
//   v3     [38732, 38932)    relu(W3@v2b+b3)
#define WS_H     0
#define WS_AS    12000
#define WS_AD    12250
#define WS_EX    12500
#define WS_ROWP  16750
#define WS_SLOT  17004
#define WS_VRAW  21504
#define WS_V1    33504
#define WS_V2    37532
#define WS_V2B   38332
#define WS_V3    38732

// ---------------------------------------------------------------------------
// K1: per-node prep. grid=250 blocks, 64 threads.
//  h[n][f] = dot(x[n,:], Wg[f,:]);  a_s[n], a_d[n] wave-reduced.
__global__ void k1_prep(const float* __restrict__ x, const float* __restrict__ wg,
                        const float* __restrict__ att_src, const float* __restrict__ att_dst,
                        const float* __restrict__ roh, const float* __restrict__ pssm,
                        float* __restrict__ ws) {
    const int n = blockIdx.x;
    const int f = threadIdx.x;
    float hv = 0.f;
    if (f < OUT_F) {
        const float* xr = x + n * IN_F;
        const float* wr = wg + f * IN_F;
        #pragma unroll
        for (int k = 0; k < IN_F; ++k) hv += xr[k] * wr[k];
        ws[WS_H + n * OUT_F + f] = hv;
    }
    float cs = (f < OUT_F) ? hv * att_src[f] : 0.f;
    float cd = (f < OUT_F) ? hv * att_dst[f] : 0.f;
    #pragma unroll
    for (int o = 32; o > 0; o >>= 1) {
        cs += __shfl_down(cs, o);
        cd += __shfl_down(cd, o);
    }
    if (f == 0) {
        ws[WS_AS + n] = cs;
        ws[WS_AD + n] = cd;
    }
    if (n == 0 && f < 28) ws[WS_V1 + f] = (f < 8) ? roh[f] : pssm[f - 8];
}

// ---------------------------------------------------------------------------
// K2: single block, 1024 threads. Computes per-edge ex[] (leaky_relu + exp;
// segment_max dropped: softmax shift-invariant, logits bounded) AND builds a
// CSR over dst (count -> prefix -> scatter) entirely in LDS. No global atomics.
__global__ void k2_csr(const int* __restrict__ ei, float* __restrict__ ws) {
    __shared__ int cnt[N_NODES];
    __shared__ int rowp[N_NODES + 1];
    __shared__ int pos[N_NODES];
    const int tid = threadIdx.x;
    const int nt  = blockDim.x;
    for (int i = tid; i < N_NODES; i += nt) cnt[i] = 0;
    __syncthreads();
    const float* a_s = ws + WS_AS;
    const float* a_d = ws + WS_AD;
    float* ex = ws + WS_EX;
    for (int e = tid; e < E_TOT; e += nt) {
        int s, d;
        if (e < E_EDGES) { s = ei[e]; d = ei[E_EDGES + e]; }
        else             { s = d = e - E_EDGES; }
        atomicAdd(&cnt[d], 1);                       // LDS atomic
        float val = a_s[s] + a_d[d];
        val = (val > 0.f) ? val : 0.2f * val;        // leaky_relu 0.2
        ex[e] = expf(val);
    }
    __syncthreads();
    if (tid == 0) {
        int run = 0;
        for (int i = 0; i < N_NODES; ++i) { rowp[i] = run; run += cnt[i]; }
        rowp[N_NODES] = run;
    }
    __syncthreads();
    int* rowp_g = (int*)(ws + WS_ROWP);
    for (int i = tid; i <= N_NODES; i += nt) { rowp_g[i] = rowp[i]; }
    for (int i = tid; i < N_NODES; i += nt)  { pos[i] = rowp[i]; }
    __syncthreads();
    int* slots = (int*)(ws + WS_SLOT);
    for (int e = tid; e < E_TOT; e += nt) {
        int d;
        if (e < E_EDGES) d = ei[E_EDGES + e];
        else             d = e - E_EDGES;
        int p = atomicAdd(&pos[d], 1);               // LDS atomic
        slots[p] = e;
    }
}

// ---------------------------------------------------------------------------
// K3: gather per dst node — zero atomics. Block n: load its edge list chunk
// into LDS, reduce denom, then 48 lanes accumulate features.
// vraw[n][f] = b_gat[f] + (sum ex*h_src)/(denom+eps)
__global__ void k3_gather(const int* __restrict__ ei, const float* __restrict__ b_gat,
                          float* __restrict__ ws) {
    const int n = blockIdx.x;
    const int t = threadIdx.x;       // 64
    const int* rowp  = (const int*)(ws + WS_ROWP);
    const int* slots = (const int*)(ws + WS_SLOT);
    __shared__ int   s_src[64];
    __shared__ float s_ex[64];
    const int lo = rowp[n], hi = rowp[n + 1];
    float acc = 0.f;     // feature accumulator (lane t = feature t, t<48)
    float den = 0.f;
    for (int base = lo; base < hi; base += 64) {
        const int m = min(64, hi - base);
        if (t < m) {
            int e = slots[base + t];
            s_src[t] = (e < E_EDGES) ? ei[e] : e - E_EDGES;
            s_ex[t]  = ws[WS_EX + e];
        }
        __syncthreads();
        float dv = (t < m) ? s_ex[t] : 0.f;
        #pragma unroll
        for (int o = 32; o > 0; o >>= 1) dv += __shfl_down(dv, o);
        den += __shfl(dv, 0);
        if (t < OUT_F) {
            for (int j = 0; j < m; ++j)
                acc += s_ex[j] * ws[WS_H + s_src[j] * OUT_F + t];
        }
        __syncthreads();
    }
    if (t < OUT_F)
        ws[WS_VRAW + n * OUT_F + t] = b_gat[t] + acc / (den + EPS_F);
}

// ---------------------------------------------------------------------------
// Row-parallel matvec: one 64-lane wave per output row, 16B vector loads,
// nontemporal on W (streamed once, keep v hot in L2/L3), single accumulator.
template <int C, bool RELU_IN, bool RELU_OUT>
__global__ void matvec(const float* __restrict__ W, const float* __restrict__ b,
                       const float* __restrict__ vin, float* __restrict__ vout,
                       int rows) {
    const int wv   = threadIdx.x >> 6;
    const int lane = threadIdx.x & 63;
    const int row  = blockIdx.x * (blockDim.x >> 6) + wv;
    if (row >= rows) return;
    const fx4*    Wr = reinterpret_cast<const fx4*>(W + (size_t)row * C);
    const float4* vi = reinterpret_cast<const float4*>(vin);
    constexpr int C4 = C / 4;
    float acc = 0.f;
    #pragma unroll 4
    for (int i = lane; i < C4; i += 64) {
        fx4    w = __builtin_nontemporal_load(&Wr[i]);
        float4 v = vi[i];
        if (RELU_IN) {
            v.x = fmaxf(v.x, 0.f); v.y = fmaxf(v.y, 0.f);
            v.z = fmaxf(v.z, 0.f); v.w = fmaxf(v.w, 0.f);
        }
        acc += w.x * v.x + w.y * v.y + w.z * v.z + w.w * v.w;
    }
    #pragma unroll
    for (int o = 32; o > 0; o >>= 1) acc += __shfl_down(acc, o);
    if (lane == 0) {
        float r = acc + b[row];
        vout[row] = RELU_OUT ? fmaxf(r, 0.f) : r;
    }
}

// ---------------------------------------------------------------------------
// Final layer: W4 (1x200) dot — one wave.
__global__ void k_w4(const float* __restrict__ W4, const float* __restrict__ b4,
                     const float* __restrict__ v3, float* __restrict__ out) {
    const int lane = threadIdx.x & 63;
    const float4* W4v = reinterpret_cast<const float4*>(W4);
    const float4* v3v = reinterpret_cast<const float4*>(v3);
    float acc = 0.f;
    for (int i = lane; i < 50; i += 64) {
        float4 w = W4v[i], v = v3v[i];
        acc += w.x * v.x + w.y * v.y + w.z * v.z + w.w * v.w;
    }
    #pragma unroll
    for (int o = 32; o > 0; o >>= 1) acc += __shfl_down(acc, o);
    if (lane == 0) out[0] = acc + b4[0];
}

// ---------------------------------------------------------------------------
extern "C" void kernel_launch(void* const* d_in, const int* in_sizes, int n_in,
                              void* d_out, int out_size, void* d_ws, size_t ws_size,
                              hipStream_t stream) {
    const float* x       = (const float*)d_in[0];
    const int*   ei      = (const int*)  d_in[1];
    // d_in[2] = edge_weight (unused by reference)
    const float* roh     = (const float*)d_in[3];
    const float* pssm    = (const float*)d_in[4];
    const float* wg      = (const float*)d_in[5];
    const float* att_src = (const float*)d_in[6];
    const float* att_dst = (const float*)d_in[7];
    const float* b_gat   = (const float*)d_in[8];
    const float* W0 = (const float*)d_in[9];   const float* b0 = (const float*)d_in[10];
    const float* W1 = (const float*)d_in[11];  const float* b1 = (const float*)d_in[12];
    const float* W2 = (const float*)d_in[13];  const float* b2 = (const float*)d_in[14];
    const float* W3 = (const float*)d_in[15];  const float* b3 = (const float*)d_in[16];
    const float* W4 = (const float*)d_in[17];  const float* b4 = (const float*)d_in[18];

    float* ws  = (float*)d_ws;
    float* out = (float*)d_out;

    // GAT (no global atomics anywhere)
    k1_prep<<<N_NODES, 64, 0, stream>>>(x, wg, att_src, att_dst, roh, pssm, ws);
    k2_csr<<<1, 1024, 0, stream>>>(ei, ws);
    k3_gather<<<N_NODES, 64, 0, stream>>>(ei, b_gat, ws);

    // MLP
    // W0: 4000x12000, relu(GAT out) folded into load, relu out -> v1[28:]
    matvec<12000, true,  true><<<1000, 256, 0, stream>>>(W0, b0, ws + WS_VRAW, ws + WS_V1 + 28, 4000);
    // W1: 800x4028
    matvec<4028,  false, true><<<200,  256, 0, stream>>>(W1, b1, ws + WS_V1, ws + WS_V2, 800);
    // W2: 400x800
    matvec<800,   false, true><<<100,  256, 0, stream>>>(W2, b2, ws + WS_V2, ws + WS_V2B, 400);
    // W3: 200x400
    matvec<400,   false, true><<<50,   256, 0, stream>>>(W3, b3, ws + WS_V2B, ws + WS_V3, 200);
    // W4: 1x200 final dot
    k_w4<<<1, 64, 0, stream>>>(W4, b4, ws + WS_V3, out);
}